// Round 3
// baseline (1325.184 us; speedup 1.0000x reference)
//
#include <hip/hip_runtime.h>
#include <stdint.h>

// SparseDecoder: 4-layer masked MLP forward.
//   x:[64,512] fp32; layer i: K=SIZES[i] -> N=SIZES[i+1]
//   z_i = x @ (W_i * mask_i)^T + b_i ; relu between layers (applied on READ
//   by the next layer's GEMM; each GEMM stores pre-activation z).
// Memory-bound stream of W(fp32) + mask. Compute: bf16 MFMA 16x16x32 with
// fp32 accumulate (error ~5e-5 vs 9.2e-4 threshold; the network is strongly
// attenuating so bf16 is ample). atomicAdd K-split partials into
// bias-initialized z buffers.
//
// MASK DTYPE: round-1/2 bit-identical absmax (1.42e-2) under a precision
// change proved a structural mask misread; quantitative fit says masks are
// int32 (bool -> "integer -> const int*"). A probe kernel detects the layout
// at runtime (all upper bytes zero => int32) and the GEMM branches uniformly.

typedef short bf16x8 __attribute__((ext_vector_type(8)));   // 8 bf16 (4 VGPRs)
typedef float f32x4  __attribute__((ext_vector_type(4)));   // 4 fp32 acc

#define LDSS 136   // LDS row stride in bf16 elems: 128 + 8 pad (272B)

__device__ __forceinline__ unsigned short f2bf(float f) {
    // round-to-nearest-even fp32 -> bf16 (finite inputs)
    unsigned int u = __float_as_uint(f);
    return (unsigned short)((u + 0x7FFFu + ((u >> 16) & 1u)) >> 16);
}

// Detect mask storage: writes flag=1 if masks are 1-byte bools, 0 if int32.
// Scans first 16 KB of mask0 (>=1MB under either layout, so always in
// bounds). int32 bools (0/1) have all upper 3 bytes zero; u8 bools have a
// nonzero upper byte in ~14% of words -> P(misdetect) ~ e^-631.
__global__ __launch_bounds__(256) void probe_mask_kind(
    const unsigned int* __restrict__ m, int* __restrict__ flag)
{
    __shared__ int s_any;
    if (threadIdx.x == 0) s_any = 0;
    __syncthreads();
    int any = 0;
    #pragma unroll
    for (int it = 0; it < 16; ++it) {
        unsigned int v = m[it * 256 + threadIdx.x];
        if (v & 0xFFFFFF00u) any = 1;
    }
    if (__any(any) && (threadIdx.x & 63) == 0) s_any = 1;
    __syncthreads();
    if (threadIdx.x == 0) flag[0] = s_any;   // 1 => u8 bools, 0 => int32
}

// Broadcast biases into all four z buffers in one launch.
// grid = (120, 64): 120*256 = 30720 = 2048+4096+8192+16384 cols, y = batch.
__global__ __launch_bounds__(256) void init_bias_all(
    const float* __restrict__ b0, const float* __restrict__ b1,
    const float* __restrict__ b2, const float* __restrict__ b3,
    float* __restrict__ z0, float* __restrict__ z1,
    float* __restrict__ z2, float* __restrict__ z3)
{
    int n = blockIdx.x * 256 + threadIdx.x;
    int b = blockIdx.y;
    if (n < 2048)             z0[(size_t)b * 2048  + n]           = b0[n];
    else if (n < 6144)        z1[(size_t)b * 4096  + (n - 2048)]  = b1[n - 2048];
    else if (n < 14336)       z2[(size_t)b * 8192  + (n - 6144)]  = b2[n - 6144];
    else                      z3[(size_t)b * 16384 + (n - 14336)] = b3[n - 14336];
}

// One block: 64 n-rows x 64 batches, K-range [y*kper, (y+1)*kper).
// 256 threads = 4 waves; wave w computes n-rows [w*16, w*16+16).
// K-chunk 128: stage x[64][128] and (W*mask)[64][128] as bf16 in LDS.
__global__ __launch_bounds__(256, 4) void sparse_gemm(
    const float* __restrict__ X,            // [64, K] pre-activation input
    const float* __restrict__ W,            // [N, K]
    const unsigned char* __restrict__ Mk,   // [N, K] mask (u8 or i32)
    const int* __restrict__ mflag,          // 1 => u8, 0 => i32
    float* __restrict__ Z,                  // [64, N], bias-initialized
    int N, int K, int kper, int relu_in)
{
    __shared__ unsigned short lw[64 * LDSS];  // (W*mask) bf16 tile
    __shared__ unsigned short xs[64 * LDSS];  // x bf16 tile

    const int tid  = threadIdx.x;
    const int n0   = blockIdx.x * 64;
    const int kbeg = blockIdx.y * kper;
    const int kend = kbeg + kper;

    const int wv   = tid >> 6;    // wave 0..3
    const int l    = tid & 63;
    const int lr   = l & 15;      // A: m-row / B: batch-col
    const int quad = l >> 4;      // 0..3

    const int mask_u8 = *mflag;   // uniform
    const int* __restrict__ Mk32 = (const int*)Mk;

    f32x4 acc[4];
    #pragma unroll
    for (int i = 0; i < 4; ++i) acc[i] = (f32x4){0.f, 0.f, 0.f, 0.f};

    const int c_row = tid >> 5;          // 0..7; +8 per staging iter
    const int c_col = (tid & 31) * 4;    // 0..124, 4-elem granule

    for (int k0 = kbeg; k0 < kend; k0 += 128) {
        __syncthreads();  // protect LDS reuse from previous chunk's reads

        // --- stage (W*mask) -> lw : 64 rows x 128 cols ---
        if (mask_u8) {
            #pragma unroll
            for (int it = 0; it < 8; ++it) {
                int r = c_row + it * 8;
                size_t e = (size_t)(n0 + r) * K + k0 + c_col;
                float4 w4 = *(const float4*)(W + e);
                uchar4 m4 = *(const uchar4*)(Mk + e);
                ushort4 pk;
                pk.x = m4.x ? f2bf(w4.x) : (unsigned short)0;
                pk.y = m4.y ? f2bf(w4.y) : (unsigned short)0;
                pk.z = m4.z ? f2bf(w4.z) : (unsigned short)0;
                pk.w = m4.w ? f2bf(w4.w) : (unsigned short)0;
                *(ushort4*)&lw[r * LDSS + c_col] = pk;
            }
        } else {
            #pragma unroll
            for (int it = 0; it < 8; ++it) {
                int r = c_row + it * 8;
                size_t e = (size_t)(n0 + r) * K + k0 + c_col;
                float4 w4 = *(const float4*)(W + e);
                int4   m4 = *(const int4*)(Mk32 + e);
                ushort4 pk;
                pk.x = m4.x ? f2bf(w4.x) : (unsigned short)0;
                pk.y = m4.y ? f2bf(w4.y) : (unsigned short)0;
                pk.z = m4.z ? f2bf(w4.z) : (unsigned short)0;
                pk.w = m4.w ? f2bf(w4.w) : (unsigned short)0;
                *(ushort4*)&lw[r * LDSS + c_col] = pk;
            }
        }

        // --- stage x -> xs : 64 rows x 128 cols (relu on read) ---
        #pragma unroll
        for (int it = 0; it < 8; ++it) {
            int r = c_row + it * 8;
            const float* gx = X + (size_t)r * K + k0 + c_col;
            float4 x4 = *(const float4*)gx;
            if (relu_in) {
                x4.x = fmaxf(x4.x, 0.f); x4.y = fmaxf(x4.y, 0.f);
                x4.z = fmaxf(x4.z, 0.f); x4.w = fmaxf(x4.w, 0.f);
            }
            ushort4 pk;
            pk.x = f2bf(x4.x); pk.y = f2bf(x4.y);
            pk.z = f2bf(x4.z); pk.w = f2bf(x4.w);
            *(ushort4*)&xs[r * LDSS + c_col] = pk;
        }

        __syncthreads();

        // --- MFMA: A = W rows [wv*16..+16), B = x^T, 4 k-steps of 32 ---
        const unsigned short* wrow = &lw[(wv * 16 + lr) * LDSS];
        #pragma unroll
        for (int kk = 0; kk < 4; ++kk) {
            int ko = kk * 32 + quad * 8;   // lane's 8 consecutive k
            bf16x8 a = *(const bf16x8*)&wrow[ko];
            #pragma unroll
            for (int bg = 0; bg < 4; ++bg) {
                bf16x8 bfr = *(const bf16x8*)&xs[(bg * 16 + lr) * LDSS + ko];
                acc[bg] = __builtin_amdgcn_mfma_f32_16x16x32_bf16(a, bfr, acc[bg], 0, 0, 0);
            }
        }
    }

    // --- epilogue: D layout col=lane&15 (batch), row=quad*4+reg (n) ---
    #pragma unroll
    for (int bg = 0; bg < 4; ++bg) {
        int b = bg * 16 + lr;
        float* zp = Z + (size_t)b * N + n0 + wv * 16 + quad * 4;
        #pragma unroll
        for (int r = 0; r < 4; ++r) atomicAdd(&zp[r], acc[bg][r]);
    }
}

extern "C" void kernel_launch(void* const* d_in, const int* in_sizes, int n_in,
                              void* d_out, int out_size, void* d_ws, size_t ws_size,
                              hipStream_t stream) {
    // setup_inputs order: x, W0,b0,mask0, W1,b1,mask1, W2,b2,mask2, W3,b3,mask3
    const float* x  = (const float*)d_in[0];
    const float* W0 = (const float*)d_in[1];
    const float* b0 = (const float*)d_in[2];
    const unsigned char* m0 = (const unsigned char*)d_in[3];
    const float* W1 = (const float*)d_in[4];
    const float* b1 = (const float*)d_in[5];
    const unsigned char* m1 = (const unsigned char*)d_in[6];
    const float* W2 = (const float*)d_in[7];
    const float* b2 = (const float*)d_in[8];
    const unsigned char* m2 = (const unsigned char*)d_in[9];
    const float* W3 = (const float*)d_in[10];
    const float* b3 = (const float*)d_in[11];
    const unsigned char* m3 = (const unsigned char*)d_in[12];

    float* z0 = (float*)d_ws;              // [64, 2048]
    float* z1 = z0 + (size_t)64 * 2048;    // [64, 4096]
    float* z2 = z1 + (size_t)64 * 4096;    // [64, 8192]
    float* z3 = (float*)d_out;             // [64, 16384]
    int* mflag = (int*)(z2 + (size_t)64 * 8192);  // 1 int after z2 in ws

    probe_mask_kind<<<1, 256, 0, stream>>>((const unsigned int*)m0, mflag);
    init_bias_all<<<dim3(120, 64), 256, 0, stream>>>(b0, b1, b2, b3, z0, z1, z2, z3);

    // layer 0: K=512,  N=2048 : grid (32, 4),  kper=128
    sparse_gemm<<<dim3(32, 4), 256, 0, stream>>>(x,  W0, m0, mflag, z0, 2048, 512, 128, 0);
    // layer 1: K=2048, N=4096 : grid (64, 8),  kper=256
    sparse_gemm<<<dim3(64, 8), 256, 0, stream>>>(z0, W1, m1, mflag, z1, 4096, 2048, 256, 1);
    // layer 2: K=4096, N=8192 : grid (128, 8), kper=512
    sparse_gemm<<<dim3(128, 8), 256, 0, stream>>>(z1, W2, m2, mflag, z2, 8192, 4096, 512, 1);
    // layer 3: K=8192, N=16384: grid (256, 4), kper=2048
    sparse_gemm<<<dim3(256, 4), 256, 0, stream>>>(z2, W3, m3, mflag, z3, 16384, 8192, 2048, 1);
}